// Round 7
// baseline (329.215 us; speedup 1.0000x reference)
//
#include <hip/hip_runtime.h>

// MultiHeadAttention B=4 T=2048 C=1024 H=16 D=64 — f16 MFMA pipeline.
// Stages: cvt(x,Wa,Wp)->f16; GEMM1 qkv=x*Wa^T (f16 out); flash attn (f16 out);
// GEMM2 out=y*Wp^T+b (f32 out).
// Attn v7: v6 (swapped QK^T/PV, in-register P, exp2 unnormalized softmax,
// ones-row MFMA row-sum) + 2-phase pipeline: K double-buffered in LDS,
// gl_lds(kb+1) issued BEFORE compute(kb), LDS-only publish barrier for sVt
// (no vmcnt drain), single full-drain __syncthreads at iter end. XCD-aware
// block remap: each XCD exclusively owns 8 bh -> K/V L2-resident per XCD.

typedef _Float16 f16x8 __attribute__((ext_vector_type(8)));
typedef _Float16 f16x4 __attribute__((ext_vector_type(4)));
typedef _Float16 f16x2 __attribute__((ext_vector_type(2)));
typedef float f32x4 __attribute__((ext_vector_type(4)));

__device__ __forceinline__ void gl_lds16(const _Float16* g, _Float16* l) {
  __builtin_amdgcn_global_load_lds(
      (const __attribute__((address_space(1))) void*)g,
      (__attribute__((address_space(3))) void*)l, 16, 0, 0);
}

// ---------------- f32 -> f16 convert (vectorized, grid-stride) ----------------
__global__ __launch_bounds__(256) void cvt_f32_f16(const float* __restrict__ src,
                                                   _Float16* __restrict__ dst, int n) {
  int i = (blockIdx.x * 256 + threadIdx.x) * 8;
  int stride = gridDim.x * 256 * 8;
  for (; i < n; i += stride) {
    float4 a = *(const float4*)(src + i);
    float4 b = *(const float4*)(src + i + 4);
    f16x8 o = {(_Float16)a.x, (_Float16)a.y, (_Float16)a.z, (_Float16)a.w,
               (_Float16)b.x, (_Float16)b.y, (_Float16)b.z, (_Float16)b.w};
    *(f16x8*)(dst + i) = o;
  }
}

// ---------------- GEMM: C[M,N] = A[M,K] * B[N,K]^T (+bias) --------------------
template <bool BIAS, bool OUT_F16>
__global__ __launch_bounds__(256)
void gemm_bt(const _Float16* __restrict__ A, const _Float16* __restrict__ B,
             void* __restrict__ C, const float* __restrict__ bias,
             int M, int N, int K) {
  __shared__ _Float16 sA[128 * 32];
  __shared__ _Float16 sB[128 * 32];
  const int tid = threadIdx.x;
  const int w = tid >> 6, l = tid & 63, l15 = l & 15, l4 = l >> 4;
  const int wm = w >> 1, wn = w & 1;
  const size_t m0 = (size_t)blockIdx.y * 128, n0 = (size_t)blockIdx.x * 128;

  f32x4 acc[4][4] = {};

  const int sr = tid >> 2, sc = (tid & 3) * 8;
  const _Float16* aSrc = A + (m0 + sr) * (size_t)K + sc;
  const _Float16* bSrc = B + (n0 + sr) * (size_t)K + sc;
  _Float16* aDst = sA + tid * 8;
  _Float16* bDst = sB + tid * 8;
  const int K64 = 64 * K;

  for (int k0 = 0; k0 < K; k0 += 32) {
    __syncthreads();
    gl_lds16(aSrc + k0, aDst);
    gl_lds16(aSrc + K64 + k0, aDst + 2048);
    gl_lds16(bSrc + k0, bDst);
    gl_lds16(bSrc + K64 + k0, bDst + 2048);
    __syncthreads();
    f16x8 af[4], bf[4];
#pragma unroll
    for (int i = 0; i < 4; ++i) {
      af[i] = *(const f16x8*)(sA + (wm * 64 + i * 16 + l15) * 32 + l4 * 8);
      bf[i] = *(const f16x8*)(sB + (wn * 64 + i * 16 + l15) * 32 + l4 * 8);
    }
#pragma unroll
    for (int i = 0; i < 4; ++i)
#pragma unroll
      for (int j = 0; j < 4; ++j)
        acc[i][j] = __builtin_amdgcn_mfma_f32_16x16x32_f16(af[i], bf[j], acc[i][j], 0, 0, 0);
  }

#pragma unroll
  for (int i = 0; i < 4; ++i)
#pragma unroll
    for (int j = 0; j < 4; ++j) {
      size_t row = m0 + wm * 64 + i * 16 + l4 * 4;
      size_t col = n0 + wn * 64 + j * 16 + l15;
      float bv = 0.0f;
      if (BIAS) bv = bias[col];
#pragma unroll
      for (int rr = 0; rr < 4; ++rr) {
        float v = acc[i][j][rr] + bv;
        if (OUT_F16)
          ((_Float16*)C)[(row + rr) * N + col] = (_Float16)v;
        else
          ((float*)C)[(row + rr) * N + col] = v;
      }
    }
}

// ---------------- Flash attention v7 ------------------------------------------
// grid 1024 blocks (16 qtiles x 64 b*h, XCD-remapped), 256 thr = 4 waves.
// S^T = mfma(K, Q): lane (l15,l4) holds S for q-row l15 (+16*qs), keys l4*4+r.
// PV: Y^T = mfma(A=V^T frag from sVt, B=P frag from regs); output col=l15=
// q-row. p = exp2(s) unnormalized; l via ones-row MFMA; y = accy/l at the end.
__global__ __launch_bounds__(256, 4)
void attn_kernel(const _Float16* __restrict__ qkv, _Float16* __restrict__ y16) {
  // XCD remap: lin%8 = xcd (round-robin dispatch); each xcd owns 8 bh values.
  const int lin = blockIdx.x;
  const int xcd = lin & 7;
  const int bh = xcd * 8 + (lin >> 7);
  const int qt = (lin >> 3) & 15;
  const int b = bh >> 4, h = bh & 15;
  const int tid = threadIdx.x;
  const int w = tid >> 6, l = tid & 63, l15 = l & 15, l4 = l >> 4;

  __shared__ _Float16 sK[2 * 128 * 64];  // double-buffered [key][64], XOR-swizzled
  __shared__ _Float16 sVt[64][136];      // V^T [d][key], padded

  const size_t rowbase = (size_t)b * 2048;
  const int qcol = h * 64, kcol = 1024 + h * 64, vcol = 2048 + h * 64;

  // Q as B-operand, pre-scaled by 1/sqrt(D) * log2(e) (exp2-domain softmax)
  f16x8 bq[2][2];
  {
    const _Float16 csf = (_Float16)(0.125f * 1.44269504f);
#pragma unroll
    for (int qs = 0; qs < 2; ++qs) {
      size_t qrow = rowbase + qt * 128 + w * 32 + qs * 16 + l15;
#pragma unroll
      for (int ks = 0; ks < 2; ++ks) {
        f16x8 v = *(const f16x8*)(qkv + qrow * 3072 + qcol + ks * 32 + l4 * 8);
#pragma unroll
        for (int e = 0; e < 8; ++e) v[e] *= csf;
        bq[qs][ks] = v;
      }
    }
  }

  f32x4 accy[2][4] = {};  // Y^T: [qs][dt], col=l15=q-row, row=l4*4+r=d
  f32x4 accl[2] = {};     // row-sum via ones-row MFMA: row 0 = sum(P-row)

  // ones-row A-operand: A[row=l15][k] = (l15==0) ? 1 : 0
  const _Float16 one0 = (l15 == 0) ? (_Float16)1.0f : (_Float16)0.0f;
  const f16x4 bv1 = {one0, one0, one0, one0};

  // K staging via global_load_lds, dest linear in lane order; source chunk
  // pre-swizzled: LDS[r][c] = G[r][c ^ (r&7)] (involution; read applies same XOR)
  const int krow = w * 8 + (l >> 3);                  // +j*32 per issue
  const int csrc = (l & 7) ^ (l >> 3);
  const _Float16* kSrc0 = qkv + (rowbase + krow) * 3072 + kcol + csrc * 8;
  _Float16* kDst0 = sK + w * 8 * 64 + l * 8;          // +buf*8192 +j*2048

  // V transpose staging: lane l of wave w owns key pair (2l, 2l+1), d in
  // [16w, 16w+16). Pack same-d values of the two keys into one dword and
  // ds_write_b32 at sVt[d][2l] — per slot all 64 lanes hit the SAME row.
  const int vrow = 2 * l, vd0 = w * 16;
  const _Float16* vSrc0 = qkv + (rowbase + vrow) * 3072 + vcol + vd0;

  // ---- prologue: stage K(0) into buf0; V(0) into regs; publish ----
  f16x8 va0 = *(const f16x8*)(vSrc0);
  f16x8 va1 = *(const f16x8*)(vSrc0 + 8);
  f16x8 vb0 = *(const f16x8*)(vSrc0 + 3072);
  f16x8 vb1 = *(const f16x8*)(vSrc0 + 3072 + 8);
#pragma unroll
  for (int j = 0; j < 4; ++j) gl_lds16(kSrc0 + (size_t)j * 32 * 3072, kDst0 + j * 2048);
  __syncthreads();  // drains vmcnt: K(0) + V(0) ready

  for (int kb = 0; kb < 16; ++kb) {
    const int cur = kb & 1;
    // issue next tile's K staging FIRST — latency spans this tile's compute.
    // nbuf held K(kb-1), whose readers finished before the prev trailing sync.
    if (kb + 1 < 16) {
      const _Float16* kn = kSrc0 + (size_t)(kb + 1) * 128 * 3072;
      _Float16* kd = kDst0 + (cur ^ 1) * 8192;
#pragma unroll
      for (int j = 0; j < 4; ++j) gl_lds16(kn + (size_t)j * 32 * 3072, kd + j * 2048);
    }
    // V(kb) regs -> sVt (prev PV readers done before prev trailing sync)
#pragma unroll
    for (int e = 0; e < 8; ++e) {
      f16x2 p0; p0[0] = va0[e]; p0[1] = vb0[e];
      *(f16x2*)(&sVt[vd0 + e][vrow]) = p0;
      f16x2 p1; p1[0] = va1[e]; p1[1] = vb1[e];
      *(f16x2*)(&sVt[vd0 + 8 + e][vrow]) = p1;
    }
    // V(kb+1) -> regs (in flight through this tile's compute)
    if (kb + 1 < 16) {
      const _Float16* vs_ = vSrc0 + (size_t)(kb + 1) * 128 * 3072;
      va0 = *(const f16x8*)(vs_);
      va1 = *(const f16x8*)(vs_ + 8);
      vb0 = *(const f16x8*)(vs_ + 3072);
      vb1 = *(const f16x8*)(vs_ + 3072 + 8);
    }
    // publish sVt: LDS-only wait + raw barrier — do NOT drain vmcnt here.
    asm volatile("s_waitcnt lgkmcnt(0)" ::: "memory");
    __builtin_amdgcn_s_barrier();
    __builtin_amdgcn_sched_barrier(0);

    const _Float16* sKc = sK + cur * 8192;
#pragma unroll
    for (int sub = 0; sub < 2; ++sub) {
      // S^T = K * Q^T over this 64-key sub-tile
      f32x4 st[2][4] = {};
      __builtin_amdgcn_s_setprio(1);
#pragma unroll
      for (int m = 0; m < 4; ++m) {
        const int row = sub * 64 + m * 16 + l15;
#pragma unroll
        for (int ks = 0; ks < 2; ++ks) {
          const int cs_ = (ks * 4 + l4) ^ (l15 & 7);
          f16x8 ak = *(const f16x8*)(sKc + row * 64 + cs_ * 8);
          st[0][m] = __builtin_amdgcn_mfma_f32_16x16x32_f16(ak, bq[0][ks], st[0][m], 0, 0, 0);
          st[1][m] = __builtin_amdgcn_mfma_f32_16x16x32_f16(ak, bq[1][ks], st[1][m], 0, 0, 0);
        }
      }
      __builtin_amdgcn_s_setprio(0);

      // unnormalized softmax: p = exp2(s), packed straight into PV fragments
      f16x4 pa[2][4];
#pragma unroll
      for (int qs = 0; qs < 2; ++qs) {
#pragma unroll
        for (int m = 0; m < 4; ++m) {
          float p0 = exp2f(st[qs][m][0]);
          float p1 = exp2f(st[qs][m][1]);
          float p2 = exp2f(st[qs][m][2]);
          float p3 = exp2f(st[qs][m][3]);
#if __has_builtin(__builtin_amdgcn_cvt_pkrtz)
          auto lo = __builtin_amdgcn_cvt_pkrtz(p0, p1);
          auto hi = __builtin_amdgcn_cvt_pkrtz(p2, p3);
          f16x4 pv;
          pv[0] = lo[0]; pv[1] = lo[1]; pv[2] = hi[0]; pv[3] = hi[1];
          pa[qs][m] = pv;
#else
          f16x4 pv;
          pv[0] = (_Float16)p0; pv[1] = (_Float16)p1;
          pv[2] = (_Float16)p2; pv[3] = (_Float16)p3;
          pa[qs][m] = pv;
#endif
        }
      }

      // Y^T += V^T * P^T  (16x16x16: A = V^T frag from LDS, B = P frag);
      // row-sum += ones-row * P^T (lands in output row 0 = reg 0 of l4==0).
      __builtin_amdgcn_s_setprio(1);
#pragma unroll
      for (int m = 0; m < 4; ++m) {
        const int kc = sub * 64 + m * 16 + l4 * 4;
        accl[0] = __builtin_amdgcn_mfma_f32_16x16x16f16(bv1, pa[0][m], accl[0], 0, 0, 0);
        accl[1] = __builtin_amdgcn_mfma_f32_16x16x16f16(bv1, pa[1][m], accl[1], 0, 0, 0);
#pragma unroll
        for (int dt = 0; dt < 4; ++dt) {
          f16x4 bv = *(const f16x4*)(&sVt[dt * 16 + l15][kc]);
          accy[0][dt] = __builtin_amdgcn_mfma_f32_16x16x16f16(bv, pa[0][m], accy[0][dt], 0, 0, 0);
          accy[1][dt] = __builtin_amdgcn_mfma_f32_16x16x16f16(bv, pa[1][m], accy[1][dt], 0, 0, 0);
        }
      }
      __builtin_amdgcn_s_setprio(0);
    }

    // trailing full drain: publishes K(kb+1) (gl_lds vmcnt->0) and guards the
    // WAR on sVt + nbuf for the next iteration.
    __syncthreads();
  }

  // epilogue: broadcast row-sum from lane l15 (l4==0, reg 0 = row 0), divide.
#pragma unroll
  for (int qs = 0; qs < 2; ++qs) {
    const float lsum = __shfl(accl[qs][0], l15);
    const float rinv = 1.0f / lsum;
    const size_t row = rowbase + qt * 128 + w * 32 + qs * 16 + l15;
#pragma unroll
    for (int dt = 0; dt < 4; ++dt) {
      f16x4 ov;
#pragma unroll
      for (int r = 0; r < 4; ++r) ov[r] = (_Float16)(accy[qs][dt][r] * rinv);
      *(f16x4*)(y16 + row * 1024 + h * 64 + dt * 16 + l4 * 4) = ov;
    }
  }
}

// ---------------- launch -------------------------------------------------------
extern "C" void kernel_launch(void* const* d_in, const int* in_sizes, int n_in,
                              void* d_out, int out_size, void* d_ws, size_t ws_size,
                              hipStream_t stream) {
  (void)in_sizes; (void)n_in; (void)out_size; (void)ws_size;
  const float* x  = (const float*)d_in[0];   // [8192,1024]
  const float* Wa = (const float*)d_in[1];   // [3072,1024]
  const float* Wp = (const float*)d_in[2];   // [1024,1024]
  const float* bp = (const float*)d_in[3];   // [1024]
  float* out = (float*)d_out;                // [8192,1024] f32

  char* ws = (char*)d_ws;
  _Float16* x16   = (_Float16*)ws; ws += (size_t)8192 * 1024 * 2;
  _Float16* Wa16  = (_Float16*)ws; ws += (size_t)3072 * 1024 * 2;
  _Float16* Wp16  = (_Float16*)ws; ws += (size_t)1024 * 1024 * 2;
  _Float16* qkv16 = (_Float16*)ws; ws += (size_t)8192 * 3072 * 2;
  _Float16* y16   = (_Float16*)ws; ws += (size_t)8192 * 1024 * 2;

  cvt_f32_f16<<<4096, 256, 0, stream>>>(x, x16, 8192 * 1024);
  cvt_f32_f16<<<1536, 256, 0, stream>>>(Wa, Wa16, 3072 * 1024);
  cvt_f32_f16<<<512, 256, 0, stream>>>(Wp, Wp16, 1024 * 1024);

  gemm_bt<false, true><<<dim3(24, 64), 256, 0, stream>>>(x16, Wa16, (void*)qkv16, nullptr,
                                                         8192, 3072, 1024);
  attn_kernel<<<1024, 256, 0, stream>>>(qkv16, y16);
  gemm_bt<true, false><<<dim3(8, 64), 256, 0, stream>>>(y16, Wp16, (void*)out, bp,
                                                        8192, 1024, 1024);
}

// Round 8
// 285.714 us; speedup vs baseline: 1.1523x; 1.1523x over previous
//
#include <hip/hip_runtime.h>

// MultiHeadAttention B=4 T=2048 C=1024 H=16 D=64 — f16 MFMA pipeline.
// Stages: cvt(x,Wa,Wp)->f16; GEMM1 qkv=x*Wa^T (f16 out); flash attn (f16 out);
// GEMM2 out=y*Wp^T+b (f32 out).
// Attn v8 = v6 structure (proven 134us: single-buffered XOR-swizzled K,
// in-register P via swapped QK^T/PV, exp2 unnormalized softmax, ones-row MFMA
// row-sum, V reg-prefetch) + XCD remap (FETCH 150->25MB) + exp2 builtin.
// GEMM v2: BK=64 with attn-verified XOR chunk swizzle -> half the barrier
// drains per K-loop; LDS 32KB.

typedef _Float16 f16x8 __attribute__((ext_vector_type(8)));
typedef _Float16 f16x4 __attribute__((ext_vector_type(4)));
typedef _Float16 f16x2 __attribute__((ext_vector_type(2)));
typedef float f32x4 __attribute__((ext_vector_type(4)));

__device__ __forceinline__ void gl_lds16(const _Float16* g, _Float16* l) {
  __builtin_amdgcn_global_load_lds(
      (const __attribute__((address_space(1))) void*)g,
      (__attribute__((address_space(3))) void*)l, 16, 0, 0);
}

__device__ __forceinline__ float fexp2(float x) {
#if __has_builtin(__builtin_amdgcn_exp2f)
  return __builtin_amdgcn_exp2f(x);
#else
  return exp2f(x);
#endif
}

// ---------------- f32 -> f16 convert (vectorized, grid-stride) ----------------
__global__ __launch_bounds__(256) void cvt_f32_f16(const float* __restrict__ src,
                                                   _Float16* __restrict__ dst, int n) {
  int i = (blockIdx.x * 256 + threadIdx.x) * 8;
  int stride = gridDim.x * 256 * 8;
  for (; i < n; i += stride) {
    float4 a = *(const float4*)(src + i);
    float4 b = *(const float4*)(src + i + 4);
    f16x8 o = {(_Float16)a.x, (_Float16)a.y, (_Float16)a.z, (_Float16)a.w,
               (_Float16)b.x, (_Float16)b.y, (_Float16)b.z, (_Float16)b.w};
    *(f16x8*)(dst + i) = o;
  }
}

// ---------------- GEMM: C[M,N] = A[M,K] * B[N,K]^T (+bias) --------------------
// 128x128 tile, BK=64, 256 thr (4 waves 2x2). LDS [128][64] per matrix with
// chunk XOR swizzle LDS[r][c8] = G[r][c8 ^ (r&7)] (gl_lds pre-swizzled source,
// same-XOR ds_read) — same verified pattern as attn's sK.
template <bool BIAS, bool OUT_F16>
__global__ __launch_bounds__(256)
void gemm_bt(const _Float16* __restrict__ A, const _Float16* __restrict__ B,
             void* __restrict__ C, const float* __restrict__ bias,
             int M, int N, int K) {
  __shared__ _Float16 sA[128 * 64];
  __shared__ _Float16 sB[128 * 64];
  const int tid = threadIdx.x;
  const int w = tid >> 6, l = tid & 63, l15 = l & 15, l4 = l >> 4;
  const int wm = w >> 1, wn = w & 1;
  const size_t m0 = (size_t)blockIdx.y * 128, n0 = (size_t)blockIdx.x * 128;

  f32x4 acc[4][4] = {};

  // staging: row = tid>>3 (+j*32), chunk c8 = tid&7; source chunk c8^(row&7)
  const int sr = tid >> 3;
  const int sc8 = (tid & 7) ^ ((tid >> 3) & 7);
  const _Float16* aSrc = A + (m0 + sr) * (size_t)K + sc8 * 8;
  const _Float16* bSrc = B + (n0 + sr) * (size_t)K + sc8 * 8;
  _Float16* aDst = sA + tid * 8;
  _Float16* bDst = sB + tid * 8;
  const size_t K32 = 32 * (size_t)K;

  const int e7 = l15 & 7;

  for (int k0 = 0; k0 < K; k0 += 64) {
    __syncthreads();
#pragma unroll
    for (int j = 0; j < 4; ++j) {
      gl_lds16(aSrc + j * K32 + k0, aDst + j * 2048);
      gl_lds16(bSrc + j * K32 + k0, bDst + j * 2048);
    }
    __syncthreads();
#pragma unroll
    for (int ks = 0; ks < 2; ++ks) {
      const int cs_ = ((ks * 4 + l4) ^ e7) * 8;
      f16x8 af[4], bf[4];
#pragma unroll
      for (int i = 0; i < 4; ++i) {
        af[i] = *(const f16x8*)(sA + (wm * 64 + i * 16 + l15) * 64 + cs_);
        bf[i] = *(const f16x8*)(sB + (wn * 64 + i * 16 + l15) * 64 + cs_);
      }
#pragma unroll
      for (int i = 0; i < 4; ++i)
#pragma unroll
        for (int j = 0; j < 4; ++j)
          acc[i][j] = __builtin_amdgcn_mfma_f32_16x16x32_f16(af[i], bf[j], acc[i][j], 0, 0, 0);
    }
  }

#pragma unroll
  for (int i = 0; i < 4; ++i)
#pragma unroll
    for (int j = 0; j < 4; ++j) {
      size_t row = m0 + wm * 64 + i * 16 + l4 * 4;
      size_t col = n0 + wn * 64 + j * 16 + l15;
      float bv = 0.0f;
      if (BIAS) bv = bias[col];
#pragma unroll
      for (int rr = 0; rr < 4; ++rr) {
        float v = acc[i][j][rr] + bv;
        if (OUT_F16)
          ((_Float16*)C)[(row + rr) * N + col] = (_Float16)v;
        else
          ((float*)C)[(row + rr) * N + col] = v;
      }
    }
}

// ---------------- Flash attention v8 ------------------------------------------
// grid 1024 blocks (16 qtiles x 64 b*h, XCD-remapped), 256 thr = 4 waves.
// S^T = mfma(K, Q): lane (l15,l4) holds S for q-row l15 (+16*qs), keys l4*4+r.
// PV: Y^T = mfma(A=V^T frag from sVt, B=P frag from regs); output col=l15=
// q-row. p = exp2(s) unnormalized; l via ones-row MFMA; y = accy/l at the end.
__global__ __launch_bounds__(256, 4)
void attn_kernel(const _Float16* __restrict__ qkv, _Float16* __restrict__ y16) {
  // XCD remap: lin%8 = xcd (round-robin dispatch); each xcd owns 8 bh values.
  const int lin = blockIdx.x;
  const int xcd = lin & 7;
  const int bh = xcd * 8 + (lin >> 7);
  const int qt = (lin >> 3) & 15;
  const int b = bh >> 4, h = bh & 15;
  const int tid = threadIdx.x;
  const int w = tid >> 6, l = tid & 63, l15 = l & 15, l4 = l >> 4;

  __shared__ _Float16 sK[128 * 64];   // [key][64], chunk-XOR-swizzled
  __shared__ _Float16 sVt[64][136];   // V^T [d][key], padded

  const size_t rowbase = (size_t)b * 2048;
  const int qcol = h * 64, kcol = 1024 + h * 64, vcol = 2048 + h * 64;

  // Q as B-operand, pre-scaled by 1/sqrt(D) * log2(e) (exp2-domain softmax)
  f16x8 bq[2][2];
  {
    const _Float16 csf = (_Float16)(0.125f * 1.44269504f);
#pragma unroll
    for (int qs = 0; qs < 2; ++qs) {
      size_t qrow = rowbase + qt * 128 + w * 32 + qs * 16 + l15;
#pragma unroll
      for (int ks = 0; ks < 2; ++ks) {
        f16x8 v = *(const f16x8*)(qkv + qrow * 3072 + qcol + ks * 32 + l4 * 8);
#pragma unroll
        for (int e = 0; e < 8; ++e) v[e] *= csf;
        bq[qs][ks] = v;
      }
    }
  }

  f32x4 accy[2][4] = {};  // Y^T: [qs][dt], col=l15=q-row, row=l4*4+r=d
  f32x4 accl[2] = {};     // row-sum via ones-row MFMA: row 0 = sum(P-row)

  // ones-row A-operand: A[row=l15][k] = (l15==0) ? 1 : 0
  const _Float16 one0 = (l15 == 0) ? (_Float16)1.0f : (_Float16)0.0f;
  const f16x4 bv1 = {one0, one0, one0, one0};

  // K staging via global_load_lds, dest linear in lane order; source chunk
  // pre-swizzled: LDS[r][c] = G[r][c ^ (r&7)] (involution; read applies same XOR)
  const int krow = w * 8 + (l >> 3);                  // +j*32 per issue
  const int csrc = (l & 7) ^ (l >> 3);
  const _Float16* kSrc0 = qkv + (rowbase + krow) * 3072 + kcol + csrc * 8;
  _Float16* kDst0 = sK + w * 8 * 64 + l * 8;          // +j*2048 per issue

  // V transpose staging: lane l of wave w owns key pair (2l, 2l+1), d in
  // [16w, 16w+16). Pack same-d values of the two keys into one dword and
  // ds_write_b32 at sVt[d][2l] — per slot all 64 lanes hit the SAME row,
  // cols 2l -> banks l%32 -> 2-way (free).
  const int vrow = 2 * l, vd0 = w * 16;
  const _Float16* vSrc0 = qkv + (rowbase + vrow) * 3072 + vcol + vd0;

  // V prefetch (one tile ahead): regs loaded after barrier2, written after
  // the NEXT barrier1 — latency hides under this tile's compute.
  f16x8 va0 = *(const f16x8*)(vSrc0);
  f16x8 va1 = *(const f16x8*)(vSrc0 + 8);
  f16x8 vb0 = *(const f16x8*)(vSrc0 + 3072);
  f16x8 vb1 = *(const f16x8*)(vSrc0 + 3072 + 8);

  for (int kb = 0; kb < 16; ++kb) {
    __syncthreads();
    {
      const _Float16* ks_ = kSrc0 + (size_t)kb * 128 * 3072;
#pragma unroll
      for (int j = 0; j < 4; ++j) gl_lds16(ks_ + (size_t)j * 32 * 3072, kDst0 + j * 2048);
#pragma unroll
      for (int e = 0; e < 8; ++e) {
        f16x2 p0; p0[0] = va0[e]; p0[1] = vb0[e];
        *(f16x2*)(&sVt[vd0 + e][vrow]) = p0;
        f16x2 p1; p1[0] = va1[e]; p1[1] = vb1[e];
        *(f16x2*)(&sVt[vd0 + 8 + e][vrow]) = p1;
      }
    }
    __syncthreads();

    // prefetch next tile's V into regs (in flight during compute below)
    if (kb + 1 < 16) {
      const _Float16* vs_ = vSrc0 + (size_t)(kb + 1) * 128 * 3072;
      va0 = *(const f16x8*)(vs_);
      va1 = *(const f16x8*)(vs_ + 8);
      vb0 = *(const f16x8*)(vs_ + 3072);
      vb1 = *(const f16x8*)(vs_ + 3072 + 8);
    }

#pragma unroll
    for (int sub = 0; sub < 2; ++sub) {
      // S^T = K * Q^T over this 64-key sub-tile
      f32x4 st[2][4] = {};
      __builtin_amdgcn_s_setprio(1);
#pragma unroll
      for (int m = 0; m < 4; ++m) {
        const int row = sub * 64 + m * 16 + l15;
#pragma unroll
        for (int ks = 0; ks < 2; ++ks) {
          const int cs_ = (ks * 4 + l4) ^ (l15 & 7);
          f16x8 ak = *(const f16x8*)(sK + row * 64 + cs_ * 8);
          st[0][m] = __builtin_amdgcn_mfma_f32_16x16x32_f16(ak, bq[0][ks], st[0][m], 0, 0, 0);
          st[1][m] = __builtin_amdgcn_mfma_f32_16x16x32_f16(ak, bq[1][ks], st[1][m], 0, 0, 0);
        }
      }
      __builtin_amdgcn_s_setprio(0);

      // unnormalized softmax: p = exp2(s), packed straight into PV fragments
      f16x4 pa[2][4];
#pragma unroll
      for (int qs = 0; qs < 2; ++qs) {
#pragma unroll
        for (int m = 0; m < 4; ++m) {
          float p0 = fexp2(st[qs][m][0]);
          float p1 = fexp2(st[qs][m][1]);
          float p2 = fexp2(st[qs][m][2]);
          float p3 = fexp2(st[qs][m][3]);
#if __has_builtin(__builtin_amdgcn_cvt_pkrtz)
          auto lo = __builtin_amdgcn_cvt_pkrtz(p0, p1);
          auto hi = __builtin_amdgcn_cvt_pkrtz(p2, p3);
          f16x4 pv;
          pv[0] = lo[0]; pv[1] = lo[1]; pv[2] = hi[0]; pv[3] = hi[1];
          pa[qs][m] = pv;
#else
          f16x4 pv;
          pv[0] = (_Float16)p0; pv[1] = (_Float16)p1;
          pv[2] = (_Float16)p2; pv[3] = (_Float16)p3;
          pa[qs][m] = pv;
#endif
        }
      }

      // Y^T += V^T * P^T  (16x16x16: A = V^T frag from LDS, B = P frag);
      // row-sum += ones-row * P^T (lands in output row 0 = reg 0 of l4==0).
      __builtin_amdgcn_s_setprio(1);
#pragma unroll
      for (int m = 0; m < 4; ++m) {
        const int kc = sub * 64 + m * 16 + l4 * 4;
        accl[0] = __builtin_amdgcn_mfma_f32_16x16x16f16(bv1, pa[0][m], accl[0], 0, 0, 0);
        accl[1] = __builtin_amdgcn_mfma_f32_16x16x16f16(bv1, pa[1][m], accl[1], 0, 0, 0);
#pragma unroll
        for (int dt = 0; dt < 4; ++dt) {
          f16x4 bv = *(const f16x4*)(&sVt[dt * 16 + l15][kc]);
          accy[0][dt] = __builtin_amdgcn_mfma_f32_16x16x16f16(bv, pa[0][m], accy[0][dt], 0, 0, 0);
          accy[1][dt] = __builtin_amdgcn_mfma_f32_16x16x16f16(bv, pa[1][m], accy[1][dt], 0, 0, 0);
        }
      }
      __builtin_amdgcn_s_setprio(0);
    }
  }

  // epilogue: broadcast row-sum from lane l15 (l4==0, reg 0 = row 0), divide.
#pragma unroll
  for (int qs = 0; qs < 2; ++qs) {
    const float lsum = __shfl(accl[qs][0], l15);
    const float rinv = 1.0f / lsum;
    const size_t row = rowbase + qt * 128 + w * 32 + qs * 16 + l15;
#pragma unroll
    for (int dt = 0; dt < 4; ++dt) {
      f16x4 ov;
#pragma unroll
      for (int r = 0; r < 4; ++r) ov[r] = (_Float16)(accy[qs][dt][r] * rinv);
      *(f16x4*)(y16 + row * 1024 + h * 64 + dt * 16 + l4 * 4) = ov;
    }
  }
}

// ---------------- launch -------------------------------------------------------
extern "C" void kernel_launch(void* const* d_in, const int* in_sizes, int n_in,
                              void* d_out, int out_size, void* d_ws, size_t ws_size,
                              hipStream_t stream) {
  (void)in_sizes; (void)n_in; (void)out_size; (void)ws_size;
  const float* x  = (const float*)d_in[0];   // [8192,1024]
  const float* Wa = (const float*)d_in[1];   // [3072,1024]
  const float* Wp = (const float*)d_in[2];   // [1024,1024]
  const float* bp = (const float*)d_in[3];   // [1024]
  float* out = (float*)d_out;                // [8192,1024] f32

  char* ws = (char*)d_ws;
  _Float16* x16   = (_Float16*)ws; ws += (size_t)8192 * 1024 * 2;
  _Float16* Wa16  = (_Float16*)ws; ws += (size_t)3072 * 1024 * 2;
  _Float16* Wp16  = (_Float16*)ws; ws += (size_t)1024 * 1024 * 2;
  _Float16* qkv16 = (_Float16*)ws; ws += (size_t)8192 * 3072 * 2;
  _Float16* y16   = (_Float16*)ws; ws += (size_t)8192 * 1024 * 2;

  cvt_f32_f16<<<4096, 256, 0, stream>>>(x, x16, 8192 * 1024);
  cvt_f32_f16<<<1536, 256, 0, stream>>>(Wa, Wa16, 3072 * 1024);
  cvt_f32_f16<<<512, 256, 0, stream>>>(Wp, Wp16, 1024 * 1024);

  gemm_bt<false, true><<<dim3(24, 64), 256, 0, stream>>>(x16, Wa16, (void*)qkv16, nullptr,
                                                         8192, 3072, 1024);
  attn_kernel<<<1024, 256, 0, stream>>>(qkv16, y16);
  gemm_bt<true, false><<<dim3(8, 64), 256, 0, stream>>>(y16, Wp16, (void*)out, bp,
                                                        8192, 1024, 1024);
}

// Round 10
// 269.927 us; speedup vs baseline: 1.2196x; 1.0585x over previous
//
#include <hip/hip_runtime.h>

// MultiHeadAttention B=4 T=2048 C=1024 H=16 D=64 — f16 MFMA pipeline.
// Stages: cvt(x,Wa,Wp)->f16; GEMM1 qkv=x*Wa^T (f16 out); flash attn (f16 out);
// GEMM2 out=y*Wp^T+b (f32 out).
// Attn v9 = v8 + key-permuted K staging: physical key pi(rho) stored at LDS
// row rho with pi swapping bits (key[4:3]=rho[3:2], key[2]=rho[4]). Then the
// per-lane S values for an m-pair form exactly the 16x16x32 B-operand
// (k = l4*8 + e -> physical key 32c+k), so PV runs at the full-K shape with
// ZERO cross-lane shuffles, and V^T reads become contiguous f16x8 (b128).
// MFMA/tile: 112 (80 at half-FLOP 16x16x16) -> 72 (all 16x16x32).
// (Round 9 bench was an infra failure; kernel resubmitted unchanged after
// re-verifying the permutation algebra.)

typedef _Float16 f16x8 __attribute__((ext_vector_type(8)));
typedef _Float16 f16x4 __attribute__((ext_vector_type(4)));
typedef _Float16 f16x2 __attribute__((ext_vector_type(2)));
typedef float f32x4 __attribute__((ext_vector_type(4)));

__device__ __forceinline__ void gl_lds16(const _Float16* g, _Float16* l) {
  __builtin_amdgcn_global_load_lds(
      (const __attribute__((address_space(1))) void*)g,
      (__attribute__((address_space(3))) void*)l, 16, 0, 0);
}

__device__ __forceinline__ float fexp2(float x) {
#if __has_builtin(__builtin_amdgcn_exp2f)
  return __builtin_amdgcn_exp2f(x);
#else
  return exp2f(x);
#endif
}

// ---------------- f32 -> f16 convert (vectorized, grid-stride) ----------------
__global__ __launch_bounds__(256) void cvt_f32_f16(const float* __restrict__ src,
                                                   _Float16* __restrict__ dst, int n) {
  int i = (blockIdx.x * 256 + threadIdx.x) * 8;
  int stride = gridDim.x * 256 * 8;
  for (; i < n; i += stride) {
    float4 a = *(const float4*)(src + i);
    float4 b = *(const float4*)(src + i + 4);
    f16x8 o = {(_Float16)a.x, (_Float16)a.y, (_Float16)a.z, (_Float16)a.w,
               (_Float16)b.x, (_Float16)b.y, (_Float16)b.z, (_Float16)b.w};
    *(f16x8*)(dst + i) = o;
  }
}

// ---------------- GEMM: C[M,N] = A[M,K] * B[N,K]^T (+bias) --------------------
// 128x128 tile, BK=64, 256 thr (4 waves 2x2). LDS [128][64] per matrix with
// chunk XOR swizzle LDS[r][c8] = G[r][c8 ^ (r&7)].
template <bool BIAS, bool OUT_F16>
__global__ __launch_bounds__(256)
void gemm_bt(const _Float16* __restrict__ A, const _Float16* __restrict__ B,
             void* __restrict__ C, const float* __restrict__ bias,
             int M, int N, int K) {
  __shared__ _Float16 sA[128 * 64];
  __shared__ _Float16 sB[128 * 64];
  const int tid = threadIdx.x;
  const int w = tid >> 6, l = tid & 63, l15 = l & 15, l4 = l >> 4;
  const int wm = w >> 1, wn = w & 1;
  const size_t m0 = (size_t)blockIdx.y * 128, n0 = (size_t)blockIdx.x * 128;

  f32x4 acc[4][4] = {};

  const int sr = tid >> 3;
  const int sc8 = (tid & 7) ^ ((tid >> 3) & 7);
  const _Float16* aSrc = A + (m0 + sr) * (size_t)K + sc8 * 8;
  const _Float16* bSrc = B + (n0 + sr) * (size_t)K + sc8 * 8;
  _Float16* aDst = sA + tid * 8;
  _Float16* bDst = sB + tid * 8;
  const size_t K32 = 32 * (size_t)K;

  const int e7 = l15 & 7;

  for (int k0 = 0; k0 < K; k0 += 64) {
    __syncthreads();
#pragma unroll
    for (int j = 0; j < 4; ++j) {
      gl_lds16(aSrc + j * K32 + k0, aDst + j * 2048);
      gl_lds16(bSrc + j * K32 + k0, bDst + j * 2048);
    }
    __syncthreads();
#pragma unroll
    for (int ks = 0; ks < 2; ++ks) {
      const int cs_ = ((ks * 4 + l4) ^ e7) * 8;
      f16x8 af[4], bf[4];
#pragma unroll
      for (int i = 0; i < 4; ++i) {
        af[i] = *(const f16x8*)(sA + (wm * 64 + i * 16 + l15) * 64 + cs_);
        bf[i] = *(const f16x8*)(sB + (wn * 64 + i * 16 + l15) * 64 + cs_);
      }
#pragma unroll
      for (int i = 0; i < 4; ++i)
#pragma unroll
        for (int j = 0; j < 4; ++j)
          acc[i][j] = __builtin_amdgcn_mfma_f32_16x16x32_f16(af[i], bf[j], acc[i][j], 0, 0, 0);
    }
  }

#pragma unroll
  for (int i = 0; i < 4; ++i)
#pragma unroll
    for (int j = 0; j < 4; ++j) {
      size_t row = m0 + wm * 64 + i * 16 + l4 * 4;
      size_t col = n0 + wn * 64 + j * 16 + l15;
      float bv = 0.0f;
      if (BIAS) bv = bias[col];
#pragma unroll
      for (int rr = 0; rr < 4; ++rr) {
        float v = acc[i][j][rr] + bv;
        if (OUT_F16)
          ((_Float16*)C)[(row + rr) * N + col] = (_Float16)v;
        else
          ((float*)C)[(row + rr) * N + col] = v;
      }
    }
}

// ---------------- Flash attention v9 ------------------------------------------
// grid 1024 blocks (16 qtiles x 64 b*h, XCD-remapped), 256 thr = 4 waves.
// S^T = mfma(K_perm, Q): lane (l15,l4) holds S for q-row l15 (+16*qs) at
// permuted S-rows; key permutation pi makes the m-pair values land exactly in
// the 16x16x32 B-operand layout (key = chunk*32 + l4*8 + (m&1)*4 + r).
// PV: Y^T = mfma32(A=V^T f16x8 from sVt, B=concat(pa[2c],pa[2c+1])).
// p = exp2(s) unnormalized; row-sum via ones-row MFMA; y = accy/l at the end.
__global__ __launch_bounds__(256, 4)
void attn_kernel(const _Float16* __restrict__ qkv, _Float16* __restrict__ y16) {
  // XCD remap: lin%8 = xcd (round-robin dispatch); each xcd owns 8 bh values.
  const int lin = blockIdx.x;
  const int xcd = lin & 7;
  const int bh = xcd * 8 + (lin >> 7);
  const int qt = (lin >> 3) & 15;
  const int b = bh >> 4, h = bh & 15;
  const int tid = threadIdx.x;
  const int w = tid >> 6, l = tid & 63, l15 = l & 15, l4 = l >> 4;

  __shared__ _Float16 sK[128 * 64];   // [S-row][64], chunk-XOR-swizzled, key-permuted
  __shared__ _Float16 sVt[64][136];   // V^T [d][key], padded, natural key order

  const size_t rowbase = (size_t)b * 2048;
  const int qcol = h * 64, kcol = 1024 + h * 64, vcol = 2048 + h * 64;

  // Q as B-operand, pre-scaled by 1/sqrt(D) * log2(e) (exp2-domain softmax)
  f16x8 bq[2][2];
  {
    const _Float16 csf = (_Float16)(0.125f * 1.44269504f);
#pragma unroll
    for (int qs = 0; qs < 2; ++qs) {
      size_t qrow = rowbase + qt * 128 + w * 32 + qs * 16 + l15;
#pragma unroll
      for (int ks = 0; ks < 2; ++ks) {
        f16x8 v = *(const f16x8*)(qkv + qrow * 3072 + qcol + ks * 32 + l4 * 8);
#pragma unroll
        for (int e = 0; e < 8; ++e) v[e] *= csf;
        bq[qs][ks] = v;
      }
    }
  }

  f32x4 accy[2][4] = {};  // Y^T: [qs][dt], col=l15=q-row, row=l4*4+r=d
  f32x4 accl[2] = {};     // row-sum via ones-row MFMA: row 0 = sum(P-row)

  // ones-row A-operand for K=32: A[row=l15][k] = (l15==0) ? 1 : 0
  const _Float16 one0 = (l15 == 0) ? (_Float16)1.0f : (_Float16)0.0f;
  const f16x8 ones8 = {one0, one0, one0, one0, one0, one0, one0, one0};

  // K staging via global_load_lds; dest LDS row rho = j*32 + w*8 + (l>>3),
  // linear lane order; SOURCE key = pi(rho): key[4:3]=rho[3:2], key[2]=rho[4],
  // key[1:0]=rho[1:0], key[6:5]=rho[6:5]. Column chunk pre-swizzled by dest
  // row: csrc = (l&7) ^ (rho&7), read applies same XOR.
  const int rho = w * 8 + (l >> 3);          // bits [4:0] of dest row
  const int pkey = (rho & 3) | ((rho & 0x10) >> 2) | ((rho & 0xC) << 1);
  const int csrc = (l & 7) ^ (l >> 3);
  const _Float16* kSrc0 = qkv + (rowbase + pkey) * 3072 + kcol + csrc * 8;
  _Float16* kDst0 = sK + w * 8 * 64 + l * 8;  // +j*2048 per issue

  // V transpose staging: lane l of wave w owns key pair (2l, 2l+1), d in
  // [16w, 16w+16). Pack same-d values of the two keys into one dword and
  // ds_write_b32 at sVt[d][2l] — per slot all 64 lanes hit the SAME row,
  // cols 2l -> banks l%32 -> 2-way (free). Natural key order.
  const int vrow = 2 * l, vd0 = w * 16;
  const _Float16* vSrc0 = qkv + (rowbase + vrow) * 3072 + vcol + vd0;

  // V prefetch (one tile ahead)
  f16x8 va0 = *(const f16x8*)(vSrc0);
  f16x8 va1 = *(const f16x8*)(vSrc0 + 8);
  f16x8 vb0 = *(const f16x8*)(vSrc0 + 3072);
  f16x8 vb1 = *(const f16x8*)(vSrc0 + 3072 + 8);

  for (int kb = 0; kb < 16; ++kb) {
    __syncthreads();
    {
      const _Float16* ks_ = kSrc0 + (size_t)kb * 128 * 3072;
#pragma unroll
      for (int j = 0; j < 4; ++j) gl_lds16(ks_ + (size_t)j * 32 * 3072, kDst0 + j * 2048);
#pragma unroll
      for (int e = 0; e < 8; ++e) {
        f16x2 p0; p0[0] = va0[e]; p0[1] = vb0[e];
        *(f16x2*)(&sVt[vd0 + e][vrow]) = p0;
        f16x2 p1; p1[0] = va1[e]; p1[1] = vb1[e];
        *(f16x2*)(&sVt[vd0 + 8 + e][vrow]) = p1;
      }
    }
    __syncthreads();

    // prefetch next tile's V into regs (in flight during compute below)
    if (kb + 1 < 16) {
      const _Float16* vs_ = vSrc0 + (size_t)(kb + 1) * 128 * 3072;
      va0 = *(const f16x8*)(vs_);
      va1 = *(const f16x8*)(vs_ + 8);
      vb0 = *(const f16x8*)(vs_ + 3072);
      vb1 = *(const f16x8*)(vs_ + 3072 + 8);
    }

#pragma unroll
    for (int sub = 0; sub < 2; ++sub) {
      // S^T = K_perm * Q^T over this 64-S-row sub-tile
      f32x4 st[2][4] = {};
      __builtin_amdgcn_s_setprio(1);
#pragma unroll
      for (int m = 0; m < 4; ++m) {
        const int row = sub * 64 + m * 16 + l15;
#pragma unroll
        for (int ks = 0; ks < 2; ++ks) {
          const int cs_ = (ks * 4 + l4) ^ (l15 & 7);
          f16x8 ak = *(const f16x8*)(sK + row * 64 + cs_ * 8);
          st[0][m] = __builtin_amdgcn_mfma_f32_16x16x32_f16(ak, bq[0][ks], st[0][m], 0, 0, 0);
          st[1][m] = __builtin_amdgcn_mfma_f32_16x16x32_f16(ak, bq[1][ks], st[1][m], 0, 0, 0);
        }
      }
      __builtin_amdgcn_s_setprio(0);

      // unnormalized softmax: p = exp2(s). The key permutation puts the
      // m-pair (2c, 2c+1) values exactly into B-operand element order
      // e = (m&1)*4 + r for keys sub*64 + c*32 + l4*8 + e.
      f16x8 pa8[2][2];
#pragma unroll
      for (int qs = 0; qs < 2; ++qs) {
#pragma unroll
        for (int c = 0; c < 2; ++c) {
          f16x4 half_[2];
#pragma unroll
          for (int mm = 0; mm < 2; ++mm) {
            const int m = 2 * c + mm;
            float p0 = fexp2(st[qs][m][0]);
            float p1 = fexp2(st[qs][m][1]);
            float p2 = fexp2(st[qs][m][2]);
            float p3 = fexp2(st[qs][m][3]);
#if __has_builtin(__builtin_amdgcn_cvt_pkrtz)
            auto lo = __builtin_amdgcn_cvt_pkrtz(p0, p1);
            auto hi = __builtin_amdgcn_cvt_pkrtz(p2, p3);
            f16x4 pv;
            pv[0] = lo[0]; pv[1] = lo[1]; pv[2] = hi[0]; pv[3] = hi[1];
            half_[mm] = pv;
#else
            f16x4 pv;
            pv[0] = (_Float16)p0; pv[1] = (_Float16)p1;
            pv[2] = (_Float16)p2; pv[3] = (_Float16)p3;
            half_[mm] = pv;
#endif
          }
          pa8[qs][c] = __builtin_shufflevector(half_[0], half_[1], 0, 1, 2, 3, 4, 5, 6, 7);
        }
      }

      // Y^T += V^T * P^T at K=32 (A = V^T f16x8 from LDS, B = pa8);
      // row-sum += ones-row * P^T (row 0 = reg 0 of l4==0).
      __builtin_amdgcn_s_setprio(1);
#pragma unroll
      for (int c = 0; c < 2; ++c) {
        const int kc = sub * 64 + c * 32 + l4 * 8;
        accl[0] = __builtin_amdgcn_mfma_f32_16x16x32_f16(ones8, pa8[0][c], accl[0], 0, 0, 0);
        accl[1] = __builtin_amdgcn_mfma_f32_16x16x32_f16(ones8, pa8[1][c], accl[1], 0, 0, 0);
#pragma unroll
        for (int dt = 0; dt < 4; ++dt) {
          f16x8 av = *(const f16x8*)(&sVt[dt * 16 + l15][kc]);
          accy[0][dt] = __builtin_amdgcn_mfma_f32_16x16x32_f16(av, pa8[0][c], accy[0][dt], 0, 0, 0);
          accy[1][dt] = __builtin_amdgcn_mfma_f32_16x16x32_f16(av, pa8[1][c], accy[1][dt], 0, 0, 0);
        }
      }
      __builtin_amdgcn_s_setprio(0);
    }
  }

  // epilogue: broadcast row-sum from lane l15 (l4==0, reg 0 = row 0), divide.
#pragma unroll
  for (int qs = 0; qs < 2; ++qs) {
    const float lsum = __shfl(accl[qs][0], l15);
    const float rinv = 1.0f / lsum;
    const size_t row = rowbase + qt * 128 + w * 32 + qs * 16 + l15;
#pragma unroll
    for (int dt = 0; dt < 4; ++dt) {
      f16x4 ov;
#pragma unroll
      for (int r = 0; r < 4; ++r) ov[r] = (_Float16)(accy[qs][dt][r] * rinv);
      *(f16x4*)(y16 + row * 1024 + h * 64 + dt * 16 + l4 * 4) = ov;
    }
  }
}

// ---------------- launch -------------------------------------------------------
extern "C" void kernel_launch(void* const* d_in, const int* in_sizes, int n_in,
                              void* d_out, int out_size, void* d_ws, size_t ws_size,
                              hipStream_t stream) {
  (void)in_sizes; (void)n_in; (void)out_size; (void)ws_size;
  const float* x  = (const float*)d_in[0];   // [8192,1024]
  const float* Wa = (const float*)d_in[1];   // [3072,1024]
  const float* Wp = (const float*)d_in[2];   // [1024,1024]
  const float* bp = (const float*)d_in[3];   // [1024]
  float* out = (float*)d_out;                // [8192,1024] f32

  char* ws = (char*)d_ws;
  _Float16* x16   = (_Float16*)ws; ws += (size_t)8192 * 1024 * 2;
  _Float16* Wa16  = (_Float16*)ws; ws += (size_t)3072 * 1024 * 2;
  _Float16* Wp16  = (_Float16*)ws; ws += (size_t)1024 * 1024 * 2;
  _Float16* qkv16 = (_Float16*)ws; ws += (size_t)8192 * 3072 * 2;
  _Float16* y16   = (_Float16*)ws; ws += (size_t)8192 * 1024 * 2;

  cvt_f32_f16<<<4096, 256, 0, stream>>>(x, x16, 8192 * 1024);
  cvt_f32_f16<<<1536, 256, 0, stream>>>(Wa, Wa16, 3072 * 1024);
  cvt_f32_f16<<<512, 256, 0, stream>>>(Wp, Wp16, 1024 * 1024);

  gemm_bt<false, true><<<dim3(24, 64), 256, 0, stream>>>(x16, Wa16, (void*)qkv16, nullptr,
                                                         8192, 3072, 1024);
  attn_kernel<<<1024, 256, 0, stream>>>(qkv16, y16);
  gemm_bt<true, false><<<dim3(8, 64), 256, 0, stream>>>(y16, Wp16, (void*)out, bp,
                                                        8192, 1024, 1024);
}